// Round 4
// baseline (7526.347 us; speedup 1.0000x reference)
//
#include <hip/hip_runtime.h>
#include <math.h>

#define DIM 32
#define BLK 256
#define JSPLIT 16   // j-chunks -> grid.y ; 16 fp64-atomic writers per out row
#define RI   4      // i-tiles per wave (64 rows)
#define ITPB (4*RI) // i-tiles per block (16 tiles = 256 rows)
#define GTT  32     // j-tiles between fp32 flushes (512 j)

typedef _Float16 half8 __attribute__((ext_vector_type(8)));
typedef float    f32x4 __attribute__((ext_vector_type(4)));

struct hl16 { half8 h; half8 l; };   // 32 B fragment record (hi + lo plane)

// out[i] = 2^(c2*||x_i||^2) * sum_j pf_j * 2^(<mf*x_i, y_j> - 64)
//   pf_j = 2^(c2*||y_j||^2 + 64)  (fp64 in prep, fp32 stored)
//   f16 hi/lo split: cm = Ah*Bh + (-64) ; cl = Ah*Bl + Al*Bh
//   f = fma(cl,2^-12,cm) ; accf += exp2(f)*pf  (hw v_exp_f32 — R18's
//   VALU polynomial exp2 was a 2x REGRESSION: poly costs ~250+ busy
//   VALU cyc/tt vs trans-pipe issue slots; hw exp2 is the right pipe.)
// R19 (this round): occupancy attack. R1 counters: 511 cyc/tt, 72%
//   VALUBusy, 28% idle at ~3 waves/SIMD. VGPR_Count=64 but true usage
//   ~176 incl. AGPRs — accd[RI][4] f64 (32 regs) was the fat. Drop it:
//   flush each GTT group via fp64 butterfly + atomicAdd directly
//   (error profile identical — fp32 spans only 512 terms either way;
//   extra cost ~8 cyc/tt of bpermute/f64-add). __launch_bounds__(BLK,4)
//   targets 4+ waves/SIMD for latency hiding.

__global__ __launch_bounds__(BLK) void rbf_prep(
    const float* __restrict__ lsp, const float* __restrict__ x,
    const float* __restrict__ y, int n, int m, int xblocks,
    double* __restrict__ acc, double* __restrict__ scale,
    float* __restrict__ pf, hl16* __restrict__ xhl, hl16* __restrict__ yhl)
{
    const double c2 = -(double)lsp[0] * 1.4426950408889634074; // -ls*log2(e)
    if ((int)blockIdx.x < xblocks) {
        const int i = blockIdx.x * BLK + threadIdx.x;
        if (i >= n) return;
        const float mf = (float)(-2.0 * c2);
        const float* xp = x + (size_t)i * DIM;
        double xs = 0.0;
        #pragma unroll
        for (int d = 0; d < DIM; ++d) { double v = (double)xp[d]; xs = fma(v, v, xs); }
        acc[i] = 0.0;
        scale[i] = exp2(c2 * xs);
        const int it = i >> 4, r15 = i & 15;
        #pragma unroll
        for (int q = 0; q < 4; ++q) {
            half8 hh, hl;
            #pragma unroll
            for (int d = 0; d < 8; ++d) {
                float v = xp[q * 8 + d] * mf;
                _Float16 h = (_Float16)v;
                hh[d] = h;
                hl[d] = (_Float16)((v - (float)h) * 4096.0f);
            }
            xhl[it * 64 + q * 16 + r15].h = hh;
            xhl[it * 64 + q * 16 + r15].l = hl;
        }
    } else {
        const int i = (blockIdx.x - xblocks) * BLK + threadIdx.x;
        if (i >= m) return;
        const float* yp = y + (size_t)i * DIM;
        double ys = 0.0;
        #pragma unroll
        for (int d = 0; d < DIM; ++d) { double v = (double)yp[d]; ys = fma(v, v, ys); }
        pf[i] = (float)exp2(c2 * ys + 64.0);   // 2^(bf+64), fp64-accurate
        const int it = i >> 4, r15 = i & 15;
        #pragma unroll
        for (int q = 0; q < 4; ++q) {
            half8 hh, hl;
            #pragma unroll
            for (int d = 0; d < 8; ++d) {
                float v = yp[q * 8 + d];
                _Float16 h = (_Float16)v;
                hh[d] = h;
                hl[d] = (_Float16)((v - (float)h) * 4096.0f);
            }
            yhl[it * 64 + q * 16 + r15].h = hh;
            yhl[it * 64 + q * 16 + r15].l = hl;
        }
    }
}

__global__ __launch_bounds__(BLK, 4) void rbf_main(
    const hl16* __restrict__ xhl, const hl16* __restrict__ yhl,
    const float* __restrict__ pfq, double* __restrict__ acc, int chunk_j)
{
    const int lane = threadIdx.x & 63;
    const int wave = threadIdx.x >> 6;
    const int itbase = blockIdx.x * ITPB + wave * RI;
    const int c15 = lane & 15;

    half8 ah[RI], al[RI];
    #pragma unroll
    for (int r = 0; r < RI; ++r) {
        ah[r] = xhl[(itbase + r) * 64 + lane].h;
        al[r] = xhl[(itbase + r) * 64 + lane].l;
    }

    const int jt0 = (blockIdx.y * chunk_j) >> 4;
    const int njt = chunk_j >> 4;                 // 128 j-tiles per chunk

    const f32x4 zq = {0.0f, 0.0f, 0.0f, 0.0f};            // persistent zero C
    const f32x4 nq = {-64.0f, -64.0f, -64.0f, -64.0f};    // persistent bias C
    const float k12 = 0x1p-12f;

    // uniform-pointer-bump addressing: fixed per-lane vaddr; bases bumped
    // one tile per step on the scalar pipe; load offsets imm {0,16,2048,2064}
    const hl16*  __restrict__ yp = yhl + (size_t)jt0 * 64;   // uniform base
    const float* __restrict__ bp = pfq + jt0 * 16;           // uniform base

    // 2-slot parity double-buffered B fragments
    half8 bh[2], bl[2];
    float pfv[2];
    bh[0] = yp[lane].h;
    bl[0] = yp[lane].l;
    pfv[0] = bp[c15];

    for (int g = 0; g < njt / GTT; ++g) {
        float accf[RI][4];
        #pragma unroll
        for (int r = 0; r < RI; ++r)
            #pragma unroll
            for (int e = 0; e < 4; ++e) accf[r][e] = 0.0f;

        #pragma unroll
        for (int tt = 0; tt < GTT; ++tt) {
            const int cur = tt & 1, nxt = cur ^ 1;
            // prefetch next tile (last prefetch of the last group reads one
            // tile past the chunk — never consumed; ws layout keeps it in ws)
            bh[nxt] = yp[64 + lane].h;
            bl[nxt] = yp[64 + lane].l;
            pfv[nxt] = bp[16 + c15];

            #pragma unroll
            for (int r = 0; r < RI; ++r) {
                f32x4 cm = __builtin_amdgcn_mfma_f32_16x16x32_f16(ah[r], bh[cur], nq, 0, 0, 0);
                f32x4 cl = __builtin_amdgcn_mfma_f32_16x16x32_f16(al[r], bh[cur], zq, 0, 0, 0);
                cl = __builtin_amdgcn_mfma_f32_16x16x32_f16(ah[r], bl[cur], cl, 0, 0, 0);
                #pragma unroll
                for (int e = 0; e < 4; ++e) {
                    float f = __builtin_fmaf(cl[e], k12, cm[e]);
                    float e2 = __builtin_amdgcn_exp2f(f);
                    accf[r][e] = __builtin_fmaf(e2, pfv[cur], accf[r][e]); // v_fmac
                }
            }
            yp += 64;   // one tile = 2048 B; uniform s_add on scalar pipe
            bp += 16;   // 64 B
        }

        // per-group flush: fp64 butterfly across the 16-lane col groups,
        // then fp64 atomics (replaces the accd[RI][4] f64 lane accumulators
        // — frees 32 regs/wave for occupancy)
        #pragma unroll
        for (int r = 0; r < RI; ++r) {
            #pragma unroll
            for (int e = 0; e < 4; ++e) {
                double v = (double)accf[r][e];
                v += __shfl_xor(v, 1, 64);
                v += __shfl_xor(v, 2, 64);
                v += __shfl_xor(v, 4, 64);
                v += __shfl_xor(v, 8, 64);
                if (c15 == 0) {
                    int row = (itbase + r) * 16 + (lane >> 4) * 4 + e;
                    atomicAdd(&acc[row], v);   // fp64, device-scope
                }
            }
        }
    }
}

__global__ __launch_bounds__(BLK) void rbf_finish(
    const double* __restrict__ acc, const double* __restrict__ scale,
    float* __restrict__ out, int n)
{
    int i = blockIdx.x * BLK + threadIdx.x;
    if (i < n) out[i] = (float)(acc[i] * scale[i]);
}

extern "C" void kernel_launch(void* const* d_in, const int* in_sizes, int n_in,
                              void* d_out, int out_size, void* d_ws, size_t ws_size,
                              hipStream_t stream)
{
    const float* ls = (const float*)d_in[0];
    const float* x  = (const float*)d_in[1];
    const float* y  = (const float*)d_in[2];
    const int n = in_sizes[1] / DIM;   // 32768
    const int m = in_sizes[2] / DIM;   // 32768
    float* out = (float*)d_out;

    // ws layout (ORDER MATTERS — one-past-end prefetches must stay in ws):
    //   acc[n] f64 | scale[n] f64 | pf[m] f32 | yhl | xhl   (~8.6 MB)
    char* ws = (char*)d_ws;
    double* acc   = (double*)ws;
    double* scale = acc + n;
    float*  pf    = (float*)(scale + n);
    hl16*   yhl   = (hl16*)(pf + m);
    hl16*   xhl   = yhl + (size_t)(m / 16) * 64;

    const int xblocks = (n + BLK - 1) / BLK;      // 128
    const int yblocks = (m + BLK - 1) / BLK;      // 128
    rbf_prep<<<xblocks + yblocks, BLK, 0, stream>>>(
        ls, x, y, n, m, xblocks, acc, scale, pf, xhl, yhl);

    const int chunk = m / JSPLIT;                 // 2048
    dim3 grid(n / (16 * ITPB), JSPLIT);           // 128 x 16
    rbf_main<<<grid, BLK, 0, stream>>>(xhl, yhl, pf, acc, chunk);

    rbf_finish<<<(n + BLK - 1) / BLK, BLK, 0, stream>>>(acc, scale, out, n);
}

// Round 5
// 6983.545 us; speedup vs baseline: 1.0777x; 1.0777x over previous
//
#include <hip/hip_runtime.h>
#include <math.h>

#define DIM 32
#define BLK 256
#define JSPLIT 16   // j-chunks -> grid.y ; 16 partial slots per out row
#define RI   4      // i-tiles per wave (64 rows)
#define ITPB (4*RI) // i-tiles per block (16 tiles = 256 rows)
#define GTT  32     // j-tiles between fp32 flushes (512 j)

typedef _Float16 half8 __attribute__((ext_vector_type(8)));
typedef float    f32x4 __attribute__((ext_vector_type(4)));

struct hl16 { half8 h; half8 l; };   // 32 B fragment record (hi + lo plane)

// out[i] = 2^(c2*||x_i||^2) * sum_j pf_j * 2^(<mf*x_i, y_j> - 64)
//   pf_j = 2^(c2*||y_j||^2 + 64)  (fp64 in prep, fp32 stored)
//   f16 hi/lo split: cm = Ah*Bh + (-64) ; cl = Ah*Bl + Al*Bh
//   f = fma(cl,2^-12,cm) ; accf += exp2(f)*pf  (hw v_exp_f32 — R18's
//   VALU polynomial exp2 was a 2x regression; trans pipe is right).
// R19 LESSON: per-group fp64 atomicAdd = CAS storm (synchronized flush
//   phases x cross-XCD contention -> 24 GB traffic, 7.5-38 ms). But the
//   accd removal DID raise occupancy 37->46% (unified VGPR+AGPR file).
// R20 (this round): keep the register win, kill the atomics. Private
//   fp64 partial buffer acc2[JSPLIT][n]: each (by,row) slot owned by
//   exactly ONE wave -> non-atomic RMW (g==0 stores, g>0 load+add+store).
//   finish sums the 16 partials per row. No atomics anywhere.

__global__ __launch_bounds__(BLK) void rbf_prep(
    const float* __restrict__ lsp, const float* __restrict__ x,
    const float* __restrict__ y, int n, int m, int xblocks,
    double* __restrict__ scale,
    float* __restrict__ pf, hl16* __restrict__ xhl, hl16* __restrict__ yhl)
{
    const double c2 = -(double)lsp[0] * 1.4426950408889634074; // -ls*log2(e)
    if ((int)blockIdx.x < xblocks) {
        const int i = blockIdx.x * BLK + threadIdx.x;
        if (i >= n) return;
        const float mf = (float)(-2.0 * c2);
        const float* xp = x + (size_t)i * DIM;
        double xs = 0.0;
        #pragma unroll
        for (int d = 0; d < DIM; ++d) { double v = (double)xp[d]; xs = fma(v, v, xs); }
        scale[i] = exp2(c2 * xs);
        const int it = i >> 4, r15 = i & 15;
        #pragma unroll
        for (int q = 0; q < 4; ++q) {
            half8 hh, hl;
            #pragma unroll
            for (int d = 0; d < 8; ++d) {
                float v = xp[q * 8 + d] * mf;
                _Float16 h = (_Float16)v;
                hh[d] = h;
                hl[d] = (_Float16)((v - (float)h) * 4096.0f);
            }
            xhl[it * 64 + q * 16 + r15].h = hh;
            xhl[it * 64 + q * 16 + r15].l = hl;
        }
    } else {
        const int i = (blockIdx.x - xblocks) * BLK + threadIdx.x;
        if (i >= m) return;
        const float* yp = y + (size_t)i * DIM;
        double ys = 0.0;
        #pragma unroll
        for (int d = 0; d < DIM; ++d) { double v = (double)yp[d]; ys = fma(v, v, ys); }
        pf[i] = (float)exp2(c2 * ys + 64.0);   // 2^(bf+64), fp64-accurate
        const int it = i >> 4, r15 = i & 15;
        #pragma unroll
        for (int q = 0; q < 4; ++q) {
            half8 hh, hl;
            #pragma unroll
            for (int d = 0; d < 8; ++d) {
                float v = yp[q * 8 + d];
                _Float16 h = (_Float16)v;
                hh[d] = h;
                hl[d] = (_Float16)((v - (float)h) * 4096.0f);
            }
            yhl[it * 64 + q * 16 + r15].h = hh;
            yhl[it * 64 + q * 16 + r15].l = hl;
        }
    }
}

__global__ __launch_bounds__(BLK, 4) void rbf_main(
    const hl16* __restrict__ xhl, const hl16* __restrict__ yhl,
    const float* __restrict__ pfq, double* __restrict__ acc2,
    int chunk_j, int nrows)
{
    const int lane = threadIdx.x & 63;
    const int wave = threadIdx.x >> 6;
    const int itbase = blockIdx.x * ITPB + wave * RI;
    const int c15 = lane & 15;

    half8 ah[RI], al[RI];
    #pragma unroll
    for (int r = 0; r < RI; ++r) {
        ah[r] = xhl[(itbase + r) * 64 + lane].h;
        al[r] = xhl[(itbase + r) * 64 + lane].l;
    }

    const int jt0 = (blockIdx.y * chunk_j) >> 4;
    const int njt = chunk_j >> 4;                 // 128 j-tiles per chunk

    const f32x4 zq = {0.0f, 0.0f, 0.0f, 0.0f};            // persistent zero C
    const f32x4 nq = {-64.0f, -64.0f, -64.0f, -64.0f};    // persistent bias C
    const float k12 = 0x1p-12f;

    // private partial slot base for this block's y-chunk (no atomics:
    // each (blockIdx.y, row) is owned by exactly one wave)
    double* __restrict__ accp = acc2 + (size_t)blockIdx.y * nrows;

    // uniform-pointer-bump addressing: fixed per-lane vaddr; bases bumped
    // one tile per step on the scalar pipe; load offsets imm {0,16,2048,2064}
    const hl16*  __restrict__ yp = yhl + (size_t)jt0 * 64;   // uniform base
    const float* __restrict__ bp = pfq + jt0 * 16;           // uniform base

    // 2-slot parity double-buffered B fragments
    half8 bh[2], bl[2];
    float pfv[2];
    bh[0] = yp[lane].h;
    bl[0] = yp[lane].l;
    pfv[0] = bp[c15];

    for (int g = 0; g < njt / GTT; ++g) {
        float accf[RI][4];
        #pragma unroll
        for (int r = 0; r < RI; ++r)
            #pragma unroll
            for (int e = 0; e < 4; ++e) accf[r][e] = 0.0f;

        #pragma unroll
        for (int tt = 0; tt < GTT; ++tt) {
            const int cur = tt & 1, nxt = cur ^ 1;
            // prefetch next tile (last prefetch of the last group reads one
            // tile past the chunk — never consumed; ws layout keeps it in ws)
            bh[nxt] = yp[64 + lane].h;
            bl[nxt] = yp[64 + lane].l;
            pfv[nxt] = bp[16 + c15];

            #pragma unroll
            for (int r = 0; r < RI; ++r) {
                f32x4 cm = __builtin_amdgcn_mfma_f32_16x16x32_f16(ah[r], bh[cur], nq, 0, 0, 0);
                f32x4 cl = __builtin_amdgcn_mfma_f32_16x16x32_f16(al[r], bh[cur], zq, 0, 0, 0);
                cl = __builtin_amdgcn_mfma_f32_16x16x32_f16(ah[r], bl[cur], cl, 0, 0, 0);
                #pragma unroll
                for (int e = 0; e < 4; ++e) {
                    float f = __builtin_fmaf(cl[e], k12, cm[e]);
                    float e2 = __builtin_amdgcn_exp2f(f);
                    accf[r][e] = __builtin_fmaf(e2, pfv[cur], accf[r][e]); // v_fmac
                }
            }
            yp += 64;   // one tile = 2048 B; uniform s_add on scalar pipe
            bp += 16;   // 64 B
        }

        // per-group flush: fp64 butterfly across the 16-lane col groups,
        // then NON-ATOMIC RMW into this wave's private partial slots
        // (replaces accd[RI][4] f64 lane accumulators — frees ~32 regs)
        #pragma unroll
        for (int r = 0; r < RI; ++r) {
            #pragma unroll
            for (int e = 0; e < 4; ++e) {
                double v = (double)accf[r][e];
                v += __shfl_xor(v, 1, 64);
                v += __shfl_xor(v, 2, 64);
                v += __shfl_xor(v, 4, 64);
                v += __shfl_xor(v, 8, 64);
                if (c15 == 0) {
                    int row = (itbase + r) * 16 + (lane >> 4) * 4 + e;
                    double prev = (g == 0) ? 0.0 : accp[row];
                    accp[row] = prev + v;
                }
            }
        }
    }
}

__global__ __launch_bounds__(BLK) void rbf_finish(
    const double* __restrict__ acc2, const double* __restrict__ scale,
    float* __restrict__ out, int n)
{
    int i = blockIdx.x * BLK + threadIdx.x;
    if (i >= n) return;
    double s = 0.0;
    #pragma unroll
    for (int k = 0; k < JSPLIT; ++k) s += acc2[(size_t)k * n + i];
    out[i] = (float)(s * scale[i]);
}

extern "C" void kernel_launch(void* const* d_in, const int* in_sizes, int n_in,
                              void* d_out, int out_size, void* d_ws, size_t ws_size,
                              hipStream_t stream)
{
    const float* ls = (const float*)d_in[0];
    const float* x  = (const float*)d_in[1];
    const float* y  = (const float*)d_in[2];
    const int n = in_sizes[1] / DIM;   // 32768
    const int m = in_sizes[2] / DIM;   // 32768
    float* out = (float*)d_out;

    // ws layout (ORDER MATTERS — one-past-end prefetches must stay in ws):
    //   scale[n] f64 | acc2[JSPLIT*n] f64 | pf[m] f32 | yhl | xhl  (~13 MB)
    char* ws = (char*)d_ws;
    double* scale = (double*)ws;
    double* acc2  = scale + n;
    float*  pf    = (float*)(acc2 + (size_t)JSPLIT * n);
    hl16*   yhl   = (hl16*)(pf + m);
    hl16*   xhl   = yhl + (size_t)(m / 16) * 64;

    const int xblocks = (n + BLK - 1) / BLK;      // 128
    const int yblocks = (m + BLK - 1) / BLK;      // 128
    rbf_prep<<<xblocks + yblocks, BLK, 0, stream>>>(
        ls, x, y, n, m, xblocks, scale, pf, xhl, yhl);

    const int chunk = m / JSPLIT;                 // 2048
    dim3 grid(n / (16 * ITPB), JSPLIT);           // 128 x 16
    rbf_main<<<grid, BLK, 0, stream>>>(xhl, yhl, pf, acc2, chunk, n);

    rbf_finish<<<(n + BLK - 1) / BLK, BLK, 0, stream>>>(acc2, scale, out, n);
}

// Round 6
// 5440.160 us; speedup vs baseline: 1.3835x; 1.2837x over previous
//
#include <hip/hip_runtime.h>
#include <math.h>

#define DIM 32
#define BLK 256
#define JSPLIT 16   // j-chunks -> grid.y ; 16 partial slots per out row
#define RI   4      // i-tiles per wave (64 rows)
#define ITPB (4*RI) // i-tiles per block (16 tiles = 256 rows)
#define GTT  32     // j-tiles between fp32 flushes (512 j)

typedef _Float16 half8 __attribute__((ext_vector_type(8)));
typedef float    f32x4 __attribute__((ext_vector_type(4)));

struct hl16 { half8 h; half8 l; };   // 32 B fragment record (hi + lo plane)

// out[i] = 2^(c2*||x_i||^2) * sum_j pf_j * 2^(<mf*x_i, y_j> - 64)
//   pf_j = 2^(c2*||y_j||^2 + 64)  (fp64 in prep, fp32 stored)
//   f16 hi/lo split: cm = Ah*Bh + (-64) ; cl = Ah*Bl + Al*Bh
//   f = fma(cl,2^-12,cm) ; accf += exp2(f)*pf  (hw v_exp_f32 — R18's
//   VALU polynomial exp2 was a 2x regression; trans pipe is right).
// R19/R20 LESSON (revised): the 7 ms disasters were NOT the atomics —
//   R20 had none and was identical. Culprit: __launch_bounds__(BLK,4)
//   caps the UNIFIED VGPR+AGPR allocation at 128/thread; true usage
//   ~170 (VGPR_Count=64 reports arch-VGPRs only) -> ~40 regs spilled
//   to scratch inside the j-loop -> ~44 KB/thread HBM traffic (23 GB,
//   VALUBusy 2%). Never tighten launch_bounds without checking scratch.
// R21 (this round): single-variable revert to __launch_bounds__(BLK,2)
//   (the R1 value), KEEPING R20's accd-removal (per-group fp64 butterfly
//   + non-atomic RMW into private acc2[JSPLIT][n] slots — each (by,row)
//   owned by exactly one wave; finish sums the 16 partials).

__global__ __launch_bounds__(BLK) void rbf_prep(
    const float* __restrict__ lsp, const float* __restrict__ x,
    const float* __restrict__ y, int n, int m, int xblocks,
    double* __restrict__ scale,
    float* __restrict__ pf, hl16* __restrict__ xhl, hl16* __restrict__ yhl)
{
    const double c2 = -(double)lsp[0] * 1.4426950408889634074; // -ls*log2(e)
    if ((int)blockIdx.x < xblocks) {
        const int i = blockIdx.x * BLK + threadIdx.x;
        if (i >= n) return;
        const float mf = (float)(-2.0 * c2);
        const float* xp = x + (size_t)i * DIM;
        double xs = 0.0;
        #pragma unroll
        for (int d = 0; d < DIM; ++d) { double v = (double)xp[d]; xs = fma(v, v, xs); }
        scale[i] = exp2(c2 * xs);
        const int it = i >> 4, r15 = i & 15;
        #pragma unroll
        for (int q = 0; q < 4; ++q) {
            half8 hh, hl;
            #pragma unroll
            for (int d = 0; d < 8; ++d) {
                float v = xp[q * 8 + d] * mf;
                _Float16 h = (_Float16)v;
                hh[d] = h;
                hl[d] = (_Float16)((v - (float)h) * 4096.0f);
            }
            xhl[it * 64 + q * 16 + r15].h = hh;
            xhl[it * 64 + q * 16 + r15].l = hl;
        }
    } else {
        const int i = (blockIdx.x - xblocks) * BLK + threadIdx.x;
        if (i >= m) return;
        const float* yp = y + (size_t)i * DIM;
        double ys = 0.0;
        #pragma unroll
        for (int d = 0; d < DIM; ++d) { double v = (double)yp[d]; ys = fma(v, v, ys); }
        pf[i] = (float)exp2(c2 * ys + 64.0);   // 2^(bf+64), fp64-accurate
        const int it = i >> 4, r15 = i & 15;
        #pragma unroll
        for (int q = 0; q < 4; ++q) {
            half8 hh, hl;
            #pragma unroll
            for (int d = 0; d < 8; ++d) {
                float v = yp[q * 8 + d];
                _Float16 h = (_Float16)v;
                hh[d] = h;
                hl[d] = (_Float16)((v - (float)h) * 4096.0f);
            }
            yhl[it * 64 + q * 16 + r15].h = hh;
            yhl[it * 64 + q * 16 + r15].l = hl;
        }
    }
}

__global__ __launch_bounds__(BLK, 2) void rbf_main(
    const hl16* __restrict__ xhl, const hl16* __restrict__ yhl,
    const float* __restrict__ pfq, double* __restrict__ acc2,
    int chunk_j, int nrows)
{
    const int lane = threadIdx.x & 63;
    const int wave = threadIdx.x >> 6;
    const int itbase = blockIdx.x * ITPB + wave * RI;
    const int c15 = lane & 15;

    half8 ah[RI], al[RI];
    #pragma unroll
    for (int r = 0; r < RI; ++r) {
        ah[r] = xhl[(itbase + r) * 64 + lane].h;
        al[r] = xhl[(itbase + r) * 64 + lane].l;
    }

    const int jt0 = (blockIdx.y * chunk_j) >> 4;
    const int njt = chunk_j >> 4;                 // 128 j-tiles per chunk

    const f32x4 zq = {0.0f, 0.0f, 0.0f, 0.0f};            // persistent zero C
    const f32x4 nq = {-64.0f, -64.0f, -64.0f, -64.0f};    // persistent bias C
    const float k12 = 0x1p-12f;

    // private partial slot base for this block's y-chunk (no atomics:
    // each (blockIdx.y, row) is owned by exactly one wave)
    double* __restrict__ accp = acc2 + (size_t)blockIdx.y * nrows;

    // uniform-pointer-bump addressing: fixed per-lane vaddr; bases bumped
    // one tile per step on the scalar pipe; load offsets imm {0,16,2048,2064}
    const hl16*  __restrict__ yp = yhl + (size_t)jt0 * 64;   // uniform base
    const float* __restrict__ bp = pfq + jt0 * 16;           // uniform base

    // 2-slot parity double-buffered B fragments
    half8 bh[2], bl[2];
    float pfv[2];
    bh[0] = yp[lane].h;
    bl[0] = yp[lane].l;
    pfv[0] = bp[c15];

    for (int g = 0; g < njt / GTT; ++g) {
        float accf[RI][4];
        #pragma unroll
        for (int r = 0; r < RI; ++r)
            #pragma unroll
            for (int e = 0; e < 4; ++e) accf[r][e] = 0.0f;

        #pragma unroll
        for (int tt = 0; tt < GTT; ++tt) {
            const int cur = tt & 1, nxt = cur ^ 1;
            // prefetch next tile (last prefetch of the last group reads one
            // tile past the chunk — never consumed; ws layout keeps it in ws)
            bh[nxt] = yp[64 + lane].h;
            bl[nxt] = yp[64 + lane].l;
            pfv[nxt] = bp[16 + c15];

            #pragma unroll
            for (int r = 0; r < RI; ++r) {
                f32x4 cm = __builtin_amdgcn_mfma_f32_16x16x32_f16(ah[r], bh[cur], nq, 0, 0, 0);
                f32x4 cl = __builtin_amdgcn_mfma_f32_16x16x32_f16(al[r], bh[cur], zq, 0, 0, 0);
                cl = __builtin_amdgcn_mfma_f32_16x16x32_f16(ah[r], bl[cur], cl, 0, 0, 0);
                #pragma unroll
                for (int e = 0; e < 4; ++e) {
                    float f = __builtin_fmaf(cl[e], k12, cm[e]);
                    float e2 = __builtin_amdgcn_exp2f(f);
                    accf[r][e] = __builtin_fmaf(e2, pfv[cur], accf[r][e]); // v_fmac
                }
            }
            yp += 64;   // one tile = 2048 B; uniform s_add on scalar pipe
            bp += 16;   // 64 B
        }

        // per-group flush: fp64 butterfly across the 16-lane col groups,
        // then NON-ATOMIC RMW into this wave's private partial slots
        // (replaces accd[RI][4] f64 lane accumulators — frees ~32 regs)
        #pragma unroll
        for (int r = 0; r < RI; ++r) {
            #pragma unroll
            for (int e = 0; e < 4; ++e) {
                double v = (double)accf[r][e];
                v += __shfl_xor(v, 1, 64);
                v += __shfl_xor(v, 2, 64);
                v += __shfl_xor(v, 4, 64);
                v += __shfl_xor(v, 8, 64);
                if (c15 == 0) {
                    int row = (itbase + r) * 16 + (lane >> 4) * 4 + e;
                    double prev = (g == 0) ? 0.0 : accp[row];
                    accp[row] = prev + v;
                }
            }
        }
    }
}

__global__ __launch_bounds__(BLK) void rbf_finish(
    const double* __restrict__ acc2, const double* __restrict__ scale,
    float* __restrict__ out, int n)
{
    int i = blockIdx.x * BLK + threadIdx.x;
    if (i >= n) return;
    double s = 0.0;
    #pragma unroll
    for (int k = 0; k < JSPLIT; ++k) s += acc2[(size_t)k * n + i];
    out[i] = (float)(s * scale[i]);
}

extern "C" void kernel_launch(void* const* d_in, const int* in_sizes, int n_in,
                              void* d_out, int out_size, void* d_ws, size_t ws_size,
                              hipStream_t stream)
{
    const float* ls = (const float*)d_in[0];
    const float* x  = (const float*)d_in[1];
    const float* y  = (const float*)d_in[2];
    const int n = in_sizes[1] / DIM;   // 32768
    const int m = in_sizes[2] / DIM;   // 32768
    float* out = (float*)d_out;

    // ws layout (ORDER MATTERS — one-past-end prefetches must stay in ws):
    //   scale[n] f64 | acc2[JSPLIT*n] f64 | pf[m] f32 | yhl | xhl  (~13 MB)
    char* ws = (char*)d_ws;
    double* scale = (double*)ws;
    double* acc2  = scale + n;
    float*  pf    = (float*)(acc2 + (size_t)JSPLIT * n);
    hl16*   yhl   = (hl16*)(pf + m);
    hl16*   xhl   = yhl + (size_t)(m / 16) * 64;

    const int xblocks = (n + BLK - 1) / BLK;      // 128
    const int yblocks = (m + BLK - 1) / BLK;      // 128
    rbf_prep<<<xblocks + yblocks, BLK, 0, stream>>>(
        ls, x, y, n, m, xblocks, scale, pf, xhl, yhl);

    const int chunk = m / JSPLIT;                 // 2048
    dim3 grid(n / (16 * ITPB), JSPLIT);           // 128 x 16
    rbf_main<<<grid, BLK, 0, stream>>>(xhl, yhl, pf, acc2, chunk, n);

    rbf_finish<<<(n + BLK - 1) / BLK, BLK, 0, stream>>>(acc2, scale, out, n);
}

// Round 7
// 291.856 us; speedup vs baseline: 25.7879x; 18.6399x over previous
//
#include <hip/hip_runtime.h>
#include <math.h>

#define DIM 32
#define BLK 256
#define JSPLIT 16   // j-chunks -> grid.y ; 16 fp64-atomic writers per out row
#define RI   2      // i-tiles per wave (32 rows) — R22: halved from 4 to cut
                    // per-wave regs ~130 -> ~74 => 3 -> ~6 waves/SIMD
#define ITPB (4*RI) // i-tiles per block (8 tiles = 128 rows)
#define GTT  32     // j-tiles between fp32->fp64 flushes (512 j)

typedef _Float16 half8 __attribute__((ext_vector_type(8)));
typedef float    f32x4 __attribute__((ext_vector_type(4)));

struct hl16 { half8 h; half8 l; };   // 32 B fragment record (hi + lo plane)

// out[i] = 2^(c2*||x_i||^2) * sum_j pf_j * 2^(<mf*x_i, y_j> - 64)
//   pf_j = 2^(c2*||y_j||^2 + 64)  (fp64 in prep, fp32 stored)
//   f16 hi/lo split: cm = Ah*Bh + (-64) ; cl = Ah*Bl + Al*Bh
//   f = fma(cl,2^-12,cm) ; accf += exp2(f)*pf  (hw v_exp_f32; R18's VALU
//   polynomial exp2 was a 2x regression — trans pipe is right).
//   fp32 partials -> fp64 accd every GTT tiles; ONE flush at kernel end.
// R19-R21 LESSON (final): ALL three 5-7 ms disasters shared one factor —
//   the in-g-loop flush (shfl butterfly + conditional global RMW inside
//   the loop). It blew regalloc to 128 VGPR + ~35 KB/thread scratch
//   traffic (18-23 GB HBM, VALUBusy 2%). Atomics and launch_bounds were
//   red herrings. Flush ONCE at kernel end (R1 structure) — proven.
// R22 (this round): occupancy via RI=2. R1 wall (218 us) is ~2.4x the
//   summed pipe demand => latency-bound at 3 waves/SIMD (unified-file
//   usage ~130 regs/wave). RI=2 halves ah/al+accf+accd footprint
//   (~74 regs -> ~6 waves/SIMD), grid.x doubles to 256. Same math,
//   same flush structure, same ws layout as R1.

__global__ __launch_bounds__(BLK) void rbf_prep(
    const float* __restrict__ lsp, const float* __restrict__ x,
    const float* __restrict__ y, int n, int m, int xblocks,
    double* __restrict__ acc, double* __restrict__ scale,
    float* __restrict__ pf, hl16* __restrict__ xhl, hl16* __restrict__ yhl)
{
    const double c2 = -(double)lsp[0] * 1.4426950408889634074; // -ls*log2(e)
    if ((int)blockIdx.x < xblocks) {
        const int i = blockIdx.x * BLK + threadIdx.x;
        if (i >= n) return;
        const float mf = (float)(-2.0 * c2);
        const float* xp = x + (size_t)i * DIM;
        double xs = 0.0;
        #pragma unroll
        for (int d = 0; d < DIM; ++d) { double v = (double)xp[d]; xs = fma(v, v, xs); }
        acc[i] = 0.0;
        scale[i] = exp2(c2 * xs);
        const int it = i >> 4, r15 = i & 15;
        #pragma unroll
        for (int q = 0; q < 4; ++q) {
            half8 hh, hl;
            #pragma unroll
            for (int d = 0; d < 8; ++d) {
                float v = xp[q * 8 + d] * mf;
                _Float16 h = (_Float16)v;
                hh[d] = h;
                hl[d] = (_Float16)((v - (float)h) * 4096.0f);
            }
            xhl[it * 64 + q * 16 + r15].h = hh;
            xhl[it * 64 + q * 16 + r15].l = hl;
        }
    } else {
        const int i = (blockIdx.x - xblocks) * BLK + threadIdx.x;
        if (i >= m) return;
        const float* yp = y + (size_t)i * DIM;
        double ys = 0.0;
        #pragma unroll
        for (int d = 0; d < DIM; ++d) { double v = (double)yp[d]; ys = fma(v, v, ys); }
        pf[i] = (float)exp2(c2 * ys + 64.0);   // 2^(bf+64), fp64-accurate
        const int it = i >> 4, r15 = i & 15;
        #pragma unroll
        for (int q = 0; q < 4; ++q) {
            half8 hh, hl;
            #pragma unroll
            for (int d = 0; d < 8; ++d) {
                float v = yp[q * 8 + d];
                _Float16 h = (_Float16)v;
                hh[d] = h;
                hl[d] = (_Float16)((v - (float)h) * 4096.0f);
            }
            yhl[it * 64 + q * 16 + r15].h = hh;
            yhl[it * 64 + q * 16 + r15].l = hl;
        }
    }
}

__global__ __launch_bounds__(BLK, 2) void rbf_main(
    const hl16* __restrict__ xhl, const hl16* __restrict__ yhl,
    const float* __restrict__ pfq, double* __restrict__ acc, int chunk_j)
{
    const int lane = threadIdx.x & 63;
    const int wave = threadIdx.x >> 6;
    const int itbase = blockIdx.x * ITPB + wave * RI;
    const int c15 = lane & 15;

    half8 ah[RI], al[RI];
    #pragma unroll
    for (int r = 0; r < RI; ++r) {
        ah[r] = xhl[(itbase + r) * 64 + lane].h;
        al[r] = xhl[(itbase + r) * 64 + lane].l;
    }

    const int jt0 = (blockIdx.y * chunk_j) >> 4;
    const int njt = chunk_j >> 4;                 // 128 j-tiles per chunk

    const f32x4 zq = {0.0f, 0.0f, 0.0f, 0.0f};            // persistent zero C
    const f32x4 nq = {-64.0f, -64.0f, -64.0f, -64.0f};    // persistent bias C
    const float k12 = 0x1p-12f;

    double accd[RI][4];
    #pragma unroll
    for (int r = 0; r < RI; ++r)
        #pragma unroll
        for (int e = 0; e < 4; ++e) accd[r][e] = 0.0;

    // uniform-pointer-bump addressing: fixed per-lane vaddr; bases bumped
    // one tile per step on the scalar pipe; load offsets imm {0,16,2048,2064}
    const hl16*  __restrict__ yp = yhl + (size_t)jt0 * 64;   // uniform base
    const float* __restrict__ bp = pfq + jt0 * 16;           // uniform base

    // 2-slot parity double-buffered B fragments
    half8 bh[2], bl[2];
    float pfv[2];
    bh[0] = yp[lane].h;
    bl[0] = yp[lane].l;
    pfv[0] = bp[c15];

    for (int g = 0; g < njt / GTT; ++g) {
        float accf[RI][4];
        #pragma unroll
        for (int r = 0; r < RI; ++r)
            #pragma unroll
            for (int e = 0; e < 4; ++e) accf[r][e] = 0.0f;

        #pragma unroll
        for (int tt = 0; tt < GTT; ++tt) {
            const int cur = tt & 1, nxt = cur ^ 1;
            // prefetch next tile (last prefetch of the last group reads one
            // tile past the chunk — never consumed; ws layout keeps it in ws)
            bh[nxt] = yp[64 + lane].h;
            bl[nxt] = yp[64 + lane].l;
            pfv[nxt] = bp[16 + c15];

            #pragma unroll
            for (int r = 0; r < RI; ++r) {
                f32x4 cm = __builtin_amdgcn_mfma_f32_16x16x32_f16(ah[r], bh[cur], nq, 0, 0, 0);
                f32x4 cl = __builtin_amdgcn_mfma_f32_16x16x32_f16(al[r], bh[cur], zq, 0, 0, 0);
                cl = __builtin_amdgcn_mfma_f32_16x16x32_f16(ah[r], bl[cur], cl, 0, 0, 0);
                #pragma unroll
                for (int e = 0; e < 4; ++e) {
                    float f = __builtin_fmaf(cl[e], k12, cm[e]);
                    float e2 = __builtin_amdgcn_exp2f(f);
                    accf[r][e] = __builtin_fmaf(e2, pfv[cur], accf[r][e]); // v_fmac
                }
            }
            yp += 64;   // one tile = 2048 B; uniform s_add on scalar pipe
            bp += 16;   // 64 B
        }
        #pragma unroll
        for (int r = 0; r < RI; ++r)
            #pragma unroll
            for (int e = 0; e < 4; ++e) accd[r][e] += (double)accf[r][e];
    }

    // sum the 16 j-columns: fp64 butterfly across the 16-lane col groups
    // (kernel-end only — R19-R21 proved in-loop flushes are fatal)
    #pragma unroll
    for (int r = 0; r < RI; ++r) {
        #pragma unroll
        for (int e = 0; e < 4; ++e) {
            double v = accd[r][e];
            v += __shfl_xor(v, 1, 64);
            v += __shfl_xor(v, 2, 64);
            v += __shfl_xor(v, 4, 64);
            v += __shfl_xor(v, 8, 64);
            if (c15 == 0) {
                int row = (itbase + r) * 16 + (lane >> 4) * 4 + e;
                atomicAdd(&acc[row], v);   // fp64, JSPLIT writers per row
            }
        }
    }
}

__global__ __launch_bounds__(BLK) void rbf_finish(
    const double* __restrict__ acc, const double* __restrict__ scale,
    float* __restrict__ out, int n)
{
    int i = blockIdx.x * BLK + threadIdx.x;
    if (i < n) out[i] = (float)(acc[i] * scale[i]);
}

extern "C" void kernel_launch(void* const* d_in, const int* in_sizes, int n_in,
                              void* d_out, int out_size, void* d_ws, size_t ws_size,
                              hipStream_t stream)
{
    const float* ls = (const float*)d_in[0];
    const float* x  = (const float*)d_in[1];
    const float* y  = (const float*)d_in[2];
    const int n = in_sizes[1] / DIM;   // 32768
    const int m = in_sizes[2] / DIM;   // 32768
    float* out = (float*)d_out;

    // ws layout (ORDER MATTERS — one-past-end prefetches must stay in ws):
    //   acc[n] f64 | scale[n] f64 | pf[m] f32 | yhl | xhl   (~8.6 MB)
    char* ws = (char*)d_ws;
    double* acc   = (double*)ws;
    double* scale = acc + n;
    float*  pf    = (float*)(scale + n);
    hl16*   yhl   = (hl16*)(pf + m);
    hl16*   xhl   = yhl + (size_t)(m / 16) * 64;

    const int xblocks = (n + BLK - 1) / BLK;      // 128
    const int yblocks = (m + BLK - 1) / BLK;      // 128
    rbf_prep<<<xblocks + yblocks, BLK, 0, stream>>>(
        ls, x, y, n, m, xblocks, acc, scale, pf, xhl, yhl);

    const int chunk = m / JSPLIT;                 // 2048
    dim3 grid(n / (16 * ITPB), JSPLIT);           // 256 x 16
    rbf_main<<<grid, BLK, 0, stream>>>(xhl, yhl, pf, acc, chunk);

    rbf_finish<<<(n + BLK - 1) / BLK, BLK, 0, stream>>>(acc, scale, out, n);
}

// Round 9
// 279.618 us; speedup vs baseline: 26.9166x; 1.0438x over previous
//
#include <hip/hip_runtime.h>
#include <math.h>

#define DIM 32
#define BLK 256
#define JSPLIT 16   // j-chunks -> grid.y ; 16 fp64-atomic writers per out row
#define RI   4      // i-tiles per wave (64 rows) — R22 proved RI=2 (+1 wave occ) is
                    // 8% SLOWER: exec-bound, not latency-bound. RI=4 is the sweet spot.
#define ITPB (4*RI) // i-tiles per block (16 tiles = 256 rows)
#define GTT  32     // j-tiles between fp32->fp64 flushes (512 j)

typedef _Float16 half8 __attribute__((ext_vector_type(8)));
typedef float    f32x4 __attribute__((ext_vector_type(4)));
typedef float    f32x2 __attribute__((ext_vector_type(2)));

struct hl16 { half8 h; half8 l; };   // 32 B fragment record (hi + lo plane)

// out[i] = 2^(c2*||x_i||^2) * sum_j pf_j * 2^(<mf*x_i, y_j> - 64)
//   pf_j = 2^(c2*||y_j||^2 + 64)  (fp64 in prep, fp32 stored)
//   f16 hi/lo split: cm = Ah*Bh + (-64) ; cl = Ah*Bl + Al*Bh
//   f = fma(cl,2^-12,cm) ; accf += exp2(f)*pf  (hw v_exp_f32)
//   fp32 partials -> fp64 accd every GTT tiles; ONE flush at kernel end.
// Session ledger:
//   R18: VALU polynomial exp2 = 2x regression (poly >> trans-issue cost).
//   R19-R21: in-g-loop flush (butterfly+RMW inside j-loop) = regalloc blowup
//     -> scratch spill storm (5-7 ms). Flush once at kernel end. Atomics and
//     launch_bounds were red herrings.
//   R22: RI=2 raised occupancy 37->49.5% and was 8% SLOWER -> exec-bound;
//     occupancy is NOT the lever. Trans(exp2)~50% of cycles is the floor.
// R23/R24: R1 chassis exactly (RI=4, 218 us proven), epilogue packed:
//   16 fma + 16 fmac -> 8+8 v_pk_fma_f32 via plain f32x2 vector C
//   (NO inline asm — R17's asm produced inf; NO poly — R18). Element-wise
//   IEEE-identical to R1, so absmax must be bit-identical. If gfx950 pk
//   f32 is dual-pumped: -32 cyc/tt (~6%); if half-rate: neutral.
//   (R23 submission hit GPU-acquisition timeout; identical resubmission.)

__global__ __launch_bounds__(BLK) void rbf_prep(
    const float* __restrict__ lsp, const float* __restrict__ x,
    const float* __restrict__ y, int n, int m, int xblocks,
    double* __restrict__ acc, double* __restrict__ scale,
    float* __restrict__ pf, hl16* __restrict__ xhl, hl16* __restrict__ yhl)
{
    const double c2 = -(double)lsp[0] * 1.4426950408889634074; // -ls*log2(e)
    if ((int)blockIdx.x < xblocks) {
        const int i = blockIdx.x * BLK + threadIdx.x;
        if (i >= n) return;
        const float mf = (float)(-2.0 * c2);
        const float* xp = x + (size_t)i * DIM;
        double xs = 0.0;
        #pragma unroll
        for (int d = 0; d < DIM; ++d) { double v = (double)xp[d]; xs = fma(v, v, xs); }
        acc[i] = 0.0;
        scale[i] = exp2(c2 * xs);
        const int it = i >> 4, r15 = i & 15;
        #pragma unroll
        for (int q = 0; q < 4; ++q) {
            half8 hh, hl;
            #pragma unroll
            for (int d = 0; d < 8; ++d) {
                float v = xp[q * 8 + d] * mf;
                _Float16 h = (_Float16)v;
                hh[d] = h;
                hl[d] = (_Float16)((v - (float)h) * 4096.0f);
            }
            xhl[it * 64 + q * 16 + r15].h = hh;
            xhl[it * 64 + q * 16 + r15].l = hl;
        }
    } else {
        const int i = (blockIdx.x - xblocks) * BLK + threadIdx.x;
        if (i >= m) return;
        const float* yp = y + (size_t)i * DIM;
        double ys = 0.0;
        #pragma unroll
        for (int d = 0; d < DIM; ++d) { double v = (double)yp[d]; ys = fma(v, v, ys); }
        pf[i] = (float)exp2(c2 * ys + 64.0);   // 2^(bf+64), fp64-accurate
        const int it = i >> 4, r15 = i & 15;
        #pragma unroll
        for (int q = 0; q < 4; ++q) {
            half8 hh, hl;
            #pragma unroll
            for (int d = 0; d < 8; ++d) {
                float v = yp[q * 8 + d];
                _Float16 h = (_Float16)v;
                hh[d] = h;
                hl[d] = (_Float16)((v - (float)h) * 4096.0f);
            }
            yhl[it * 64 + q * 16 + r15].h = hh;
            yhl[it * 64 + q * 16 + r15].l = hl;
        }
    }
}

__global__ __launch_bounds__(BLK, 2) void rbf_main(
    const hl16* __restrict__ xhl, const hl16* __restrict__ yhl,
    const float* __restrict__ pfq, double* __restrict__ acc, int chunk_j)
{
    const int lane = threadIdx.x & 63;
    const int wave = threadIdx.x >> 6;
    const int itbase = blockIdx.x * ITPB + wave * RI;
    const int c15 = lane & 15;

    half8 ah[RI], al[RI];
    #pragma unroll
    for (int r = 0; r < RI; ++r) {
        ah[r] = xhl[(itbase + r) * 64 + lane].h;
        al[r] = xhl[(itbase + r) * 64 + lane].l;
    }

    const int jt0 = (blockIdx.y * chunk_j) >> 4;
    const int njt = chunk_j >> 4;                 // 128 j-tiles per chunk

    const f32x4 zq = {0.0f, 0.0f, 0.0f, 0.0f};            // persistent zero C
    const f32x4 nq = {-64.0f, -64.0f, -64.0f, -64.0f};    // persistent bias C
    const f32x2 k12p = {0x1p-12f, 0x1p-12f};

    double accd[RI][4];
    #pragma unroll
    for (int r = 0; r < RI; ++r)
        #pragma unroll
        for (int e = 0; e < 4; ++e) accd[r][e] = 0.0;

    // uniform-pointer-bump addressing: fixed per-lane vaddr; bases bumped
    // one tile per step on the scalar pipe; load offsets imm {0,16,2048,2064}
    const hl16*  __restrict__ yp = yhl + (size_t)jt0 * 64;   // uniform base
    const float* __restrict__ bp = pfq + jt0 * 16;           // uniform base

    // 2-slot parity double-buffered B fragments
    half8 bh[2], bl[2];
    float pfv[2];
    bh[0] = yp[lane].h;
    bl[0] = yp[lane].l;
    pfv[0] = bp[c15];

    for (int g = 0; g < njt / GTT; ++g) {
        f32x2 acc01[RI], acc23[RI];   // packed fp32 partials {e0,e1},{e2,e3}
        #pragma unroll
        for (int r = 0; r < RI; ++r) {
            acc01[r] = (f32x2){0.0f, 0.0f};
            acc23[r] = (f32x2){0.0f, 0.0f};
        }

        #pragma unroll
        for (int tt = 0; tt < GTT; ++tt) {
            const int cur = tt & 1, nxt = cur ^ 1;
            // prefetch next tile (last prefetch of the last group reads one
            // tile past the chunk — never consumed; ws layout keeps it in ws)
            bh[nxt] = yp[64 + lane].h;
            bl[nxt] = yp[64 + lane].l;
            pfv[nxt] = bp[16 + c15];

            #pragma unroll
            for (int r = 0; r < RI; ++r) {
                f32x4 cm = __builtin_amdgcn_mfma_f32_16x16x32_f16(ah[r], bh[cur], nq, 0, 0, 0);
                f32x4 cl = __builtin_amdgcn_mfma_f32_16x16x32_f16(al[r], bh[cur], zq, 0, 0, 0);
                cl = __builtin_amdgcn_mfma_f32_16x16x32_f16(ah[r], bl[cur], cl, 0, 0, 0);
                // packed combine: f = cl*2^-12 + cm  (v_pk_fma_f32 via
                // compiler contraction; subregister extracts are free)
                f32x2 cl01 = {cl[0], cl[1]}, cl23 = {cl[2], cl[3]};
                f32x2 cm01 = {cm[0], cm[1]}, cm23 = {cm[2], cm[3]};
                f32x2 f01 = cl01 * k12p + cm01;
                f32x2 f23 = cl23 * k12p + cm23;
                // scalar hw exp2 on trans pipe (the proven-right pipe, R18)
                f32x2 e01 = { __builtin_amdgcn_exp2f(f01[0]), __builtin_amdgcn_exp2f(f01[1]) };
                f32x2 e23 = { __builtin_amdgcn_exp2f(f23[0]), __builtin_amdgcn_exp2f(f23[1]) };
                const f32x2 pfb = {pfv[cur], pfv[cur]};
                acc01[r] = e01 * pfb + acc01[r];   // packed accumulate
                acc23[r] = e23 * pfb + acc23[r];
            }
            yp += 64;   // one tile = 2048 B; uniform s_add on scalar pipe
            bp += 16;   // 64 B
        }
        #pragma unroll
        for (int r = 0; r < RI; ++r) {
            accd[r][0] += (double)acc01[r][0];
            accd[r][1] += (double)acc01[r][1];
            accd[r][2] += (double)acc23[r][0];
            accd[r][3] += (double)acc23[r][1];
        }
    }

    // sum the 16 j-columns: fp64 butterfly across the 16-lane col groups
    // (kernel-end only — R19-R21 proved in-loop flushes are fatal)
    #pragma unroll
    for (int r = 0; r < RI; ++r) {
        #pragma unroll
        for (int e = 0; e < 4; ++e) {
            double v = accd[r][e];
            v += __shfl_xor(v, 1, 64);
            v += __shfl_xor(v, 2, 64);
            v += __shfl_xor(v, 4, 64);
            v += __shfl_xor(v, 8, 64);
            if (c15 == 0) {
                int row = (itbase + r) * 16 + (lane >> 4) * 4 + e;
                atomicAdd(&acc[row], v);   // fp64, JSPLIT writers per row
            }
        }
    }
}

__global__ __launch_bounds__(BLK) void rbf_finish(
    const double* __restrict__ acc, const double* __restrict__ scale,
    float* __restrict__ out, int n)
{
    int i = blockIdx.x * BLK + threadIdx.x;
    if (i < n) out[i] = (float)(acc[i] * scale[i]);
}

extern "C" void kernel_launch(void* const* d_in, const int* in_sizes, int n_in,
                              void* d_out, int out_size, void* d_ws, size_t ws_size,
                              hipStream_t stream)
{
    const float* ls = (const float*)d_in[0];
    const float* x  = (const float*)d_in[1];
    const float* y  = (const float*)d_in[2];
    const int n = in_sizes[1] / DIM;   // 32768
    const int m = in_sizes[2] / DIM;   // 32768
    float* out = (float*)d_out;

    // ws layout (ORDER MATTERS — one-past-end prefetches must stay in ws):
    //   acc[n] f64 | scale[n] f64 | pf[m] f32 | yhl | xhl   (~8.6 MB)
    char* ws = (char*)d_ws;
    double* acc   = (double*)ws;
    double* scale = acc + n;
    float*  pf    = (float*)(scale + n);
    hl16*   yhl   = (hl16*)(pf + m);
    hl16*   xhl   = yhl + (size_t)(m / 16) * 64;

    const int xblocks = (n + BLK - 1) / BLK;      // 128
    const int yblocks = (m + BLK - 1) / BLK;      // 128
    rbf_prep<<<xblocks + yblocks, BLK, 0, stream>>>(
        ls, x, y, n, m, xblocks, acc, scale, pf, xhl, yhl);

    const int chunk = m / JSPLIT;                 // 2048
    dim3 grid(n / (16 * ITPB), JSPLIT);           // 128 x 16
    rbf_main<<<grid, BLK, 0, stream>>>(xhl, yhl, pf, acc, chunk);

    rbf_finish<<<(n + BLK - 1) / BLK, BLK, 0, stream>>>(acc, scale, out, n);
}

// Round 10
// 278.023 us; speedup vs baseline: 27.0709x; 1.0057x over previous
//
#include <hip/hip_runtime.h>
#include <math.h>

#define DIM 32
#define BLK 256
#define JSPLIT 64   // j-chunks -> grid.y ; R25: 16 -> 64. Tail-quantization fix:
                    // 2048 equal blocks on 768 co-resident slots = 2.67 cohorts
                    // -> wall rounds to 3 (12.5% drain idle). 8192 quarter-size
                    // blocks = 10.67 -> 11 quarter-cohorts (~3% loss).
#define RI   4      // i-tiles per wave (64 rows) — R22: RI=2 (+occ) was 8% slower
#define ITPB (4*RI) // i-tiles per block (16 tiles = 256 rows)
#define GTT  32     // j-tiles per fp32 accumulation group (512 j) = njt now

typedef _Float16 half8 __attribute__((ext_vector_type(8)));
typedef float    f32x4 __attribute__((ext_vector_type(4)));

struct hl16 { half8 h; half8 l; };   // 32 B fragment record (hi + lo plane)

// out[i] = 2^(c2*||x_i||^2) * sum_j pf_j * 2^(<mf*x_i, y_j> - 64)
//   pf_j = 2^(c2*||y_j||^2 + 64)  (fp64 in prep, fp32 stored)
//   f16 hi/lo split: cm = Ah*Bh + (-64) ; cl = Ah*Bl + Al*Bh
//   f = fma(cl,2^-12,cm) ; accf += exp2(f)*pf  (hw v_exp_f32)
//   fp32 partials -> fp64 accd every GTT tiles; ONE flush at kernel end.
// Session ledger (all vs the 218 us R1/R16 main):
//   R18: VALU polynomial exp2 = 2x regression (trans pipe is right).
//   R19-R21: in-j-loop flush = regalloc blowup -> scratch spill storm (5-7 ms).
//     Flush once at kernel end. Atomics / launch_bounds were red herrings.
//   R22: RI=2 raised occupancy 37->49.5%, 8% SLOWER -> exec/stall-bound,
//     occupancy not the lever.
//   R23/24: packed f32x2 epilogue: busy cycles -18% as predicted, wall +14%
//     (occ 37->30, longer dep chains). Inner loop is locally optimal; the
//     wall-vs-busy gap is NOT inner-loop stalls.
// R25 (this round): tail quantization. 37% occ = 768 co-resident blocks;
//   2048-block grid = 2.67 cohorts -> 3 cohort wall (12.5% drain idle).
//   JSPLIT=64: same total work in 8192 quarter-blocks = 11 quarter-cohorts
//   (~3% loss). Inner loop byte-identical to R1. chunk_j=512, njt=GTT=32,
//   g-loop runs once. 4x atomics (2M, staggered end-of-block — proven
//   pattern) + 4x block prologues (~0.5-1us each) are the cost.

__global__ __launch_bounds__(BLK) void rbf_prep(
    const float* __restrict__ lsp, const float* __restrict__ x,
    const float* __restrict__ y, int n, int m, int xblocks,
    double* __restrict__ acc, double* __restrict__ scale,
    float* __restrict__ pf, hl16* __restrict__ xhl, hl16* __restrict__ yhl)
{
    const double c2 = -(double)lsp[0] * 1.4426950408889634074; // -ls*log2(e)
    if ((int)blockIdx.x < xblocks) {
        const int i = blockIdx.x * BLK + threadIdx.x;
        if (i >= n) return;
        const float mf = (float)(-2.0 * c2);
        const float* xp = x + (size_t)i * DIM;
        double xs = 0.0;
        #pragma unroll
        for (int d = 0; d < DIM; ++d) { double v = (double)xp[d]; xs = fma(v, v, xs); }
        acc[i] = 0.0;
        scale[i] = exp2(c2 * xs);
        const int it = i >> 4, r15 = i & 15;
        #pragma unroll
        for (int q = 0; q < 4; ++q) {
            half8 hh, hl;
            #pragma unroll
            for (int d = 0; d < 8; ++d) {
                float v = xp[q * 8 + d] * mf;
                _Float16 h = (_Float16)v;
                hh[d] = h;
                hl[d] = (_Float16)((v - (float)h) * 4096.0f);
            }
            xhl[it * 64 + q * 16 + r15].h = hh;
            xhl[it * 64 + q * 16 + r15].l = hl;
        }
    } else {
        const int i = (blockIdx.x - xblocks) * BLK + threadIdx.x;
        if (i >= m) return;
        const float* yp = y + (size_t)i * DIM;
        double ys = 0.0;
        #pragma unroll
        for (int d = 0; d < DIM; ++d) { double v = (double)yp[d]; ys = fma(v, v, ys); }
        pf[i] = (float)exp2(c2 * ys + 64.0);   // 2^(bf+64), fp64-accurate
        const int it = i >> 4, r15 = i & 15;
        #pragma unroll
        for (int q = 0; q < 4; ++q) {
            half8 hh, hl;
            #pragma unroll
            for (int d = 0; d < 8; ++d) {
                float v = yp[q * 8 + d];
                _Float16 h = (_Float16)v;
                hh[d] = h;
                hl[d] = (_Float16)((v - (float)h) * 4096.0f);
            }
            yhl[it * 64 + q * 16 + r15].h = hh;
            yhl[it * 64 + q * 16 + r15].l = hl;
        }
    }
}

__global__ __launch_bounds__(BLK, 2) void rbf_main(
    const hl16* __restrict__ xhl, const hl16* __restrict__ yhl,
    const float* __restrict__ pfq, double* __restrict__ acc, int chunk_j)
{
    const int lane = threadIdx.x & 63;
    const int wave = threadIdx.x >> 6;
    const int itbase = blockIdx.x * ITPB + wave * RI;
    const int c15 = lane & 15;

    half8 ah[RI], al[RI];
    #pragma unroll
    for (int r = 0; r < RI; ++r) {
        ah[r] = xhl[(itbase + r) * 64 + lane].h;
        al[r] = xhl[(itbase + r) * 64 + lane].l;
    }

    const int jt0 = (blockIdx.y * chunk_j) >> 4;
    const int njt = chunk_j >> 4;                 // 32 j-tiles per chunk

    const f32x4 zq = {0.0f, 0.0f, 0.0f, 0.0f};            // persistent zero C
    const f32x4 nq = {-64.0f, -64.0f, -64.0f, -64.0f};    // persistent bias C
    const float k12 = 0x1p-12f;

    double accd[RI][4];
    #pragma unroll
    for (int r = 0; r < RI; ++r)
        #pragma unroll
        for (int e = 0; e < 4; ++e) accd[r][e] = 0.0;

    // uniform-pointer-bump addressing: fixed per-lane vaddr; bases bumped
    // one tile per step on the scalar pipe; load offsets imm {0,16,2048,2064}
    const hl16*  __restrict__ yp = yhl + (size_t)jt0 * 64;   // uniform base
    const float* __restrict__ bp = pfq + jt0 * 16;           // uniform base

    // 2-slot parity double-buffered B fragments
    half8 bh[2], bl[2];
    float pfv[2];
    bh[0] = yp[lane].h;
    bl[0] = yp[lane].l;
    pfv[0] = bp[c15];

    for (int g = 0; g < njt / GTT; ++g) {
        float accf[RI][4];
        #pragma unroll
        for (int r = 0; r < RI; ++r)
            #pragma unroll
            for (int e = 0; e < 4; ++e) accf[r][e] = 0.0f;

        #pragma unroll
        for (int tt = 0; tt < GTT; ++tt) {
            const int cur = tt & 1, nxt = cur ^ 1;
            // prefetch next tile (last prefetch of the last group reads one
            // tile past the chunk — never consumed; ws layout keeps it in ws)
            bh[nxt] = yp[64 + lane].h;
            bl[nxt] = yp[64 + lane].l;
            pfv[nxt] = bp[16 + c15];

            #pragma unroll
            for (int r = 0; r < RI; ++r) {
                f32x4 cm = __builtin_amdgcn_mfma_f32_16x16x32_f16(ah[r], bh[cur], nq, 0, 0, 0);
                f32x4 cl = __builtin_amdgcn_mfma_f32_16x16x32_f16(al[r], bh[cur], zq, 0, 0, 0);
                cl = __builtin_amdgcn_mfma_f32_16x16x32_f16(ah[r], bl[cur], cl, 0, 0, 0);
                #pragma unroll
                for (int e = 0; e < 4; ++e) {
                    float f = __builtin_fmaf(cl[e], k12, cm[e]);
                    float e2 = __builtin_amdgcn_exp2f(f);
                    accf[r][e] = __builtin_fmaf(e2, pfv[cur], accf[r][e]); // v_fmac
                }
            }
            yp += 64;   // one tile = 2048 B; uniform s_add on scalar pipe
            bp += 16;   // 64 B
        }
        #pragma unroll
        for (int r = 0; r < RI; ++r)
            #pragma unroll
            for (int e = 0; e < 4; ++e) accd[r][e] += (double)accf[r][e];
    }

    // sum the 16 j-columns: fp64 butterfly across the 16-lane col groups
    // (kernel-end only — R19-R21 proved in-loop flushes are fatal)
    #pragma unroll
    for (int r = 0; r < RI; ++r) {
        #pragma unroll
        for (int e = 0; e < 4; ++e) {
            double v = accd[r][e];
            v += __shfl_xor(v, 1, 64);
            v += __shfl_xor(v, 2, 64);
            v += __shfl_xor(v, 4, 64);
            v += __shfl_xor(v, 8, 64);
            if (c15 == 0) {
                int row = (itbase + r) * 16 + (lane >> 4) * 4 + e;
                atomicAdd(&acc[row], v);   // fp64, JSPLIT writers per row
            }
        }
    }
}

__global__ __launch_bounds__(BLK) void rbf_finish(
    const double* __restrict__ acc, const double* __restrict__ scale,
    float* __restrict__ out, int n)
{
    int i = blockIdx.x * BLK + threadIdx.x;
    if (i < n) out[i] = (float)(acc[i] * scale[i]);
}

extern "C" void kernel_launch(void* const* d_in, const int* in_sizes, int n_in,
                              void* d_out, int out_size, void* d_ws, size_t ws_size,
                              hipStream_t stream)
{
    const float* ls = (const float*)d_in[0];
    const float* x  = (const float*)d_in[1];
    const float* y  = (const float*)d_in[2];
    const int n = in_sizes[1] / DIM;   // 32768
    const int m = in_sizes[2] / DIM;   // 32768
    float* out = (float*)d_out;

    // ws layout (ORDER MATTERS — one-past-end prefetches must stay in ws):
    //   acc[n] f64 | scale[n] f64 | pf[m] f32 | yhl | xhl   (~8.6 MB)
    char* ws = (char*)d_ws;
    double* acc   = (double*)ws;
    double* scale = acc + n;
    float*  pf    = (float*)(scale + n);
    hl16*   yhl   = (hl16*)(pf + m);
    hl16*   xhl   = yhl + (size_t)(m / 16) * 64;

    const int xblocks = (n + BLK - 1) / BLK;      // 128
    const int yblocks = (m + BLK - 1) / BLK;      // 128
    rbf_prep<<<xblocks + yblocks, BLK, 0, stream>>>(
        ls, x, y, n, m, xblocks, acc, scale, pf, xhl, yhl);

    const int chunk = m / JSPLIT;                 // 512
    dim3 grid(n / (16 * ITPB), JSPLIT);           // 128 x 64
    rbf_main<<<grid, BLK, 0, stream>>>(xhl, yhl, pf, acc, chunk);

    rbf_finish<<<(n + BLK - 1) / BLK, BLK, 0, stream>>>(acc, scale, out, n);
}